// Round 4
// baseline (687.415 us; speedup 1.0000x reference)
//
#include <hip/hip_runtime.h>
#include <math.h>

// B=256, S2=32768, HID=512, HEADS=1024
// c1 = tanh(in@W_c1^T+b_c1); cx = sigmoid(c1@W_c2^T); x1 = kwta(in@W1^T+b1, cx*1024)
// x2 = kwta(x1@W2^T+b2, cx*512); x3 = kwta(x2@W3^T+b3, cx*1024); out = x3@W4^T
//
// Structure (3 launches):
//   1. hipMemsetAsync   - zero grid-barrier counters
//   2. big_gemm3        - fused (W_c1|W1) split-bf16 3-term MFMA, BM=256 (weights
//                         read ONCE), register-prefetch double buffering, split-K
//   3. mega_tail        - everything else in ONE persistent 256-block kernel with
//                         device-scope atomic grid barriers (co-residency: 256
//                         blocks x 8 waves on 256 CUs always fits)

typedef __attribute__((ext_vector_type(8))) short bf16x8;
typedef __attribute__((ext_vector_type(4))) float f32x4;
typedef __attribute__((ext_vector_type(16))) float f32x16;

__device__ __forceinline__ void split2(float f0, float f1, unsigned& hi, unsigned& lo) {
  unsigned u0 = __float_as_uint(f0), u1 = __float_as_uint(f1);
  hi = __builtin_amdgcn_perm(u1, u0, 0x07060302u);
  float r0 = f0 - __uint_as_float(u0 & 0xffff0000u);
  float r1 = f1 - __uint_as_float(u1 & 0xffff0000u);
  lo = __builtin_amdgcn_perm(__float_as_uint(r1), __float_as_uint(r0), 0x07060302u);
}

__device__ __forceinline__ void split1(float f, short& h, short& l) {
  const unsigned u = __float_as_uint(f);
  h = (short)(unsigned short)(u >> 16);
  const float r = f - __uint_as_float(u & 0xffff0000u);
  l = (short)(unsigned short)(__float_as_uint(r) >> 16);
}

// ---------------------------------------------------------------------------
// big_gemm3: P[z] = A[256,32768] @ concat(W_c1,W1)[1536,32768]^T (K-chunk z)
// BM=256 (full M: weights fetched exactly once), BN=128, BK=32, 512 threads.
// 8 waves in 4(m) x 2(n); wave tile 64x64 = 2x2 of 32x32x16 MFMA, 3 terms.
// Register-prefetch double buffering: tile s+1 global loads issued before the
// MFMA phase of tile s.
// ---------------------------------------------------------------------------
__global__ __launch_bounds__(512, 2) void big_gemm3(
    const float* __restrict__ A, const float* __restrict__ Wc1,
    const float* __restrict__ W1, float* __restrict__ P, int stepsPerZ) {
  __shared__ short sAh[256 * 40], sAl[256 * 40], sWh[128 * 40], sWl[128 * 40];
  const int tid = threadIdx.x;
  const int n0 = blockIdx.x * 128;
  const int z = blockIdx.y;
  const float* Wp = (n0 < 512) ? (Wc1 + (size_t)n0 * 32768)
                               : (W1 + (size_t)(n0 - 512) * 32768);
  const int lane = tid & 63, wv = tid >> 6;
  const int wm = wv & 3, wn = wv >> 2;
  const int l31 = lane & 31, khalf = lane >> 5;

  const int arow = tid >> 1, acol = (tid & 1) * 16;  // A: 16 floats/thread
  const int wrow = tid >> 2, wcol = (tid & 3) * 8;   // W: 8 floats/thread
  const float* Ap = A + (size_t)arow * 32768 + acol;
  const float* Wq = Wp + (size_t)wrow * 32768 + wcol;

  f32x16 acc[2][2];
#pragma unroll
  for (int i = 0; i < 2; ++i)
#pragma unroll
    for (int j = 0; j < 2; ++j)
#pragma unroll
      for (int r = 0; r < 16; ++r) acc[i][j][r] = 0.f;

  int kk = z * stepsPerZ * 32;
  float4 ra[4], rw[2];
#pragma unroll
  for (int c = 0; c < 4; ++c) ra[c] = *(const float4*)(Ap + kk + c * 4);
#pragma unroll
  for (int c = 0; c < 2; ++c) rw[c] = *(const float4*)(Wq + kk + c * 4);

  for (int s = 0; s < stepsPerZ; ++s) {
    // split prefetched regs -> LDS
#pragma unroll
    for (int c = 0; c < 4; ++c) {
      unsigned h0, l0, h1, l1;
      split2(ra[c].x, ra[c].y, h0, l0);
      split2(ra[c].z, ra[c].w, h1, l1);
      *(uint2*)(&sAh[arow * 40 + acol + c * 4]) = (uint2){h0, h1};
      *(uint2*)(&sAl[arow * 40 + acol + c * 4]) = (uint2){l0, l1};
    }
#pragma unroll
    for (int c = 0; c < 2; ++c) {
      unsigned h0, l0, h1, l1;
      split2(rw[c].x, rw[c].y, h0, l0);
      split2(rw[c].z, rw[c].w, h1, l1);
      *(uint2*)(&sWh[wrow * 40 + wcol + c * 4]) = (uint2){h0, h1};
      *(uint2*)(&sWl[wrow * 40 + wcol + c * 4]) = (uint2){l0, l1};
    }
    __syncthreads();
    // issue next tile's global loads (latency hidden by MFMA below)
    if (s + 1 < stepsPerZ) {
      const int kn = kk + 32;
#pragma unroll
      for (int c = 0; c < 4; ++c) ra[c] = *(const float4*)(Ap + kn + c * 4);
#pragma unroll
      for (int c = 0; c < 2; ++c) rw[c] = *(const float4*)(Wq + kn + c * 4);
    }
#pragma unroll
    for (int ks = 0; ks < 2; ++ks) {
      bf16x8 ah[2], al[2], wh[2], wl[2];
#pragma unroll
      for (int i = 0; i < 2; ++i) {
        const int off = (wm * 64 + i * 32 + l31) * 40 + ks * 16 + khalf * 8;
        ah[i] = *(const bf16x8*)&sAh[off];
        al[i] = *(const bf16x8*)&sAl[off];
      }
#pragma unroll
      for (int j = 0; j < 2; ++j) {
        const int off = (wn * 64 + j * 32 + l31) * 40 + ks * 16 + khalf * 8;
        wh[j] = *(const bf16x8*)&sWh[off];
        wl[j] = *(const bf16x8*)&sWl[off];
      }
#pragma unroll
      for (int i = 0; i < 2; ++i)
#pragma unroll
        for (int j = 0; j < 2; ++j) {
          acc[i][j] = __builtin_amdgcn_mfma_f32_32x32x16_bf16(ah[i], wh[j], acc[i][j], 0, 0, 0);
          acc[i][j] = __builtin_amdgcn_mfma_f32_32x32x16_bf16(ah[i], wl[j], acc[i][j], 0, 0, 0);
          acc[i][j] = __builtin_amdgcn_mfma_f32_32x32x16_bf16(al[i], wh[j], acc[i][j], 0, 0, 0);
        }
    }
    __syncthreads();
    kk += 32;
  }
  // C/D 32x32 layout: col = lane&31, row = (r&3) + 8*(r>>2) + 4*(lane>>5)
#pragma unroll
  for (int i = 0; i < 2; ++i)
#pragma unroll
    for (int j = 0; j < 2; ++j)
#pragma unroll
      for (int r = 0; r < 16; ++r) {
        const int m = wm * 64 + i * 32 + (r & 3) + 8 * (r >> 2) + 4 * khalf;
        const int n = n0 + wn * 64 + j * 32 + l31;
        P[((size_t)z * 256 + m) * 1536 + n] = acc[i][j][r];
      }
}

// ---------------------------------------------------------------------------
// Grid barrier: all 256 blocks co-resident; AGENT-scope atomics give
// cross-XCD release (L2 writeback) / acquire (L2 inv).
// ---------------------------------------------------------------------------
__device__ __forceinline__ void gbar(int* cnt, int* gen, int nblk) {
  __syncthreads();
  if (threadIdx.x == 0) {
    const int g = __hip_atomic_load(gen, __ATOMIC_RELAXED, __HIP_MEMORY_SCOPE_AGENT);
    if (__hip_atomic_fetch_add(cnt, 1, __ATOMIC_ACQ_REL, __HIP_MEMORY_SCOPE_AGENT) == nblk - 1) {
      __hip_atomic_store(cnt, 0, __ATOMIC_RELAXED, __HIP_MEMORY_SCOPE_AGENT);
      __hip_atomic_fetch_add(gen, 1, __ATOMIC_ACQ_REL, __HIP_MEMORY_SCOPE_AGENT);
    } else {
      while (__hip_atomic_load(gen, __ATOMIC_ACQUIRE, __HIP_MEMORY_SCOPE_AGENT) == g)
        __builtin_amdgcn_s_sleep(2);
    }
  }
  __syncthreads();
}

// Small-GEMM phase: C_partial[z] = X[256,K] @ W[N,K]^T (3-term split-bf16).
// 256 blocks = nBlks(n) x 4(m) x S(z); 64x128 tile, 8 waves: 4 m-strips x 2 n-halves.
__device__ __forceinline__ void gemm_phase(
    char* smem, const short* Xh, const short* Xl, const short* Wh,
    const short* Wl, float* Pout, int N, int K, int S, int nBlks) {
  short* sXh = (short*)smem;              // 64*40
  short* sXl = sXh + 2560;
  short* sWh = sXl + 2560;                // 128*40
  short* sWl = sWh + 5120;
  const int t = threadIdx.x;
  const int b = blockIdx.x;
  const int z = b / (nBlks * 4);
  const int rem = b - z * nBlks * 4;
  const int my = rem / nBlks, nx = rem - (rem / nBlks) * nBlks;
  const int m0 = my * 64, n0 = nx * 128;
  const int kPerZ = K / S, steps = kPerZ / 32;
  const int lane = t & 63, wv = t >> 6;
  const int l15 = lane & 15, q = lane >> 4;
  const int wstrip = wv & 3, wnh = wv >> 2;
  const int xrow = t >> 3, xc = (t & 7) * 4;   // X stage: 4 shorts/thread
  const int wrow = t >> 2, wc = (t & 3) * 8;   // W stage: 8 shorts/thread

  f32x4 acc[4];
#pragma unroll
  for (int j = 0; j < 4; ++j) acc[j] = (f32x4){0.f, 0.f, 0.f, 0.f};

  int kk = z * kPerZ;
  for (int s = 0; s < steps; ++s, kk += 32) {
    *(short4*)&sXh[xrow * 40 + xc] = *(const short4*)(Xh + (size_t)(m0 + xrow) * K + kk + xc);
    *(short4*)&sXl[xrow * 40 + xc] = *(const short4*)(Xl + (size_t)(m0 + xrow) * K + kk + xc);
    *(bf16x8*)&sWh[wrow * 40 + wc] = *(const bf16x8*)(Wh + (size_t)(n0 + wrow) * K + kk + wc);
    *(bf16x8*)&sWl[wrow * 40 + wc] = *(const bf16x8*)(Wl + (size_t)(n0 + wrow) * K + kk + wc);
    __syncthreads();
    const int aoff = (wstrip * 16 + l15) * 40 + q * 8;
    const bf16x8 ah = *(const bf16x8*)&sXh[aoff];
    const bf16x8 al = *(const bf16x8*)&sXl[aoff];
#pragma unroll
    for (int j = 0; j < 4; ++j) {
      const int woff = (wnh * 64 + j * 16 + l15) * 40 + q * 8;
      const bf16x8 whf = *(const bf16x8*)&sWh[woff];
      const bf16x8 wlf = *(const bf16x8*)&sWl[woff];
      acc[j] = __builtin_amdgcn_mfma_f32_16x16x32_bf16(ah, whf, acc[j], 0, 0, 0);
      acc[j] = __builtin_amdgcn_mfma_f32_16x16x32_bf16(ah, wlf, acc[j], 0, 0, 0);
      acc[j] = __builtin_amdgcn_mfma_f32_16x16x32_bf16(al, whf, acc[j], 0, 0, 0);
    }
    __syncthreads();
  }
#pragma unroll
  for (int j = 0; j < 4; ++j)
#pragma unroll
    for (int r = 0; r < 4; ++r) {
      const int m = m0 + wstrip * 16 + q * 4 + r;
      const int n = n0 + wnh * 64 + j * 16 + l15;
      Pout[((size_t)z * 256 + m) * N + n] = acc[j][r];
    }
}

// kwta phase: block = row. Reduce S partials (+bias), top-k (stable-argsort
// ties), emit bf16 hi/lo. n=512 (1 col/thread) or 1024 (2 cols/thread).
__device__ __forceinline__ void kwta_phase(
    char* smem, const float* Pin, int ldP, int colOff, int S,
    const float* bias, const float* cx, short* xh, short* xl, int n) {
  float* sdata = (float*)smem;
  const int r = blockIdx.x, t = threadIdx.x;
  const int nv = n >> 9;  // 1 or 2
  float v[2];
#pragma unroll 2
  for (int u = 0; u < nv; ++u) {
    const int c = t + u * 512;
    float s = 0.f;
    for (int z = 0; z < S; ++z) s += Pin[((size_t)z * 256 + r) * ldP + colOff + c];
    v[u] = s + bias[c];
    sdata[c] = v[u];
  }
  __syncthreads();
  const int k = (int)(cx[r] * (float)n);  // trunc matches .astype(int32)
  int cnt[2] = {0, 0};
  const float4* s4 = (const float4*)sdata;
  for (int i4 = 0; i4 < (n >> 2); ++i4) {
    const float4 e = s4[i4];
    const int b = i4 << 2;
#pragma unroll 2
    for (int u = 0; u < nv; ++u) {
      const int c = t + u * 512;
      cnt[u] += (e.x > v[u] || (e.x == v[u] && b < c));
      cnt[u] += (e.y > v[u] || (e.y == v[u] && b + 1 < c));
      cnt[u] += (e.z > v[u] || (e.z == v[u] && b + 2 < c));
      cnt[u] += (e.w > v[u] || (e.w == v[u] && b + 3 < c));
    }
  }
#pragma unroll 2
  for (int u = 0; u < nv; ++u) {
    const int c = t + u * 512;
    const float o = (cnt[u] < k) ? v[u] : 0.f;
    short h, l;
    split1(o, h, l);
    xh[(size_t)r * n + c] = h;
    xl[(size_t)r * n + c] = l;
  }
  __syncthreads();  // protect sdata before next phase reuses smem
}

// ---------------------------------------------------------------------------
// mega_tail: 256 blocks x 512 threads; phases separated by grid barriers.
// ---------------------------------------------------------------------------
__global__ __launch_bounds__(512, 2) void mega_tail(
    const float* __restrict__ Pbig, int S_big,
    const float* __restrict__ W2, const float* __restrict__ W3,
    const float* __restrict__ W4, const float* __restrict__ b_c1,
    const float* __restrict__ Wc2, const float* __restrict__ b1,
    const float* __restrict__ b2, const float* __restrict__ b3,
    int* __restrict__ sync, float* __restrict__ cx,
    short* __restrict__ x1h, short* __restrict__ x1l,
    short* __restrict__ x2h, short* __restrict__ x2l,
    short* __restrict__ x3h, short* __restrict__ x3l,
    short* __restrict__ W2h, short* __restrict__ W2l,
    short* __restrict__ W3h, short* __restrict__ W3l,
    short* __restrict__ W4h, short* __restrict__ W4l,
    float* __restrict__ Psm, float* __restrict__ out) {
  __shared__ __align__(16) char smem[30784];
  int* cnt = sync;
  int* gen = sync + 1;
  const int t = threadIdx.x, blk = blockIdx.x;
  const int nblk = gridDim.x;

  // ---- P0a: pre-split W2/W3/W4 into bf16 hi/lo (16 elems/thread)
  {
    const int g = (blk * 512 + t) * 16;
    const float* src;
    short *dh, *dl;
    int off;
    if (g < 524288) { src = W2; dh = W2h; dl = W2l; off = g; }
    else if (g < 1048576) { src = W3; dh = W3h; dl = W3l; off = g - 524288; }
    else { src = W4; dh = W4h; dl = W4l; off = g - 1048576; }
#pragma unroll
    for (int c = 0; c < 4; ++c) {
      const float4 a = *(const float4*)(src + off + c * 4);
      unsigned h0, l0, h1, l1;
      split2(a.x, a.y, h0, l0);
      split2(a.z, a.w, h1, l1);
      *(uint2*)(dh + off + c * 4) = (uint2){h0, h1};
      *(uint2*)(dl + off + c * 4) = (uint2){l0, l1};
    }
  }

  // ---- P0b: cx[r] = sigmoid( sum_c tanh(c1_pre[c]) * Wc2[c] )
  {
    float* red = (float*)(smem + 30720);
    const int r = blk;
    float s = 0.f;
    for (int z = 0; z < S_big; ++z) s += Pbig[((size_t)z * 256 + r) * 1536 + t];
    float tot = tanhf(s + b_c1[t]) * Wc2[t];
#pragma unroll
    for (int o = 32; o; o >>= 1) tot += __shfl_down(tot, o, 64);
    __syncthreads();
    if ((t & 63) == 0) red[t >> 6] = tot;
    __syncthreads();
    if (t == 0) {
      float a = 0.f;
#pragma unroll
      for (int w = 0; w < 8; ++w) a += red[w];
      cx[r] = 1.f / (1.f + expf(-a));
    }
    __syncthreads();
  }

  // ---- P1: kwta x1 (reduce Pbig cols 512..1536, +b1) -> x1h/l
  kwta_phase(smem, Pbig, 1536, 512, S_big, b1, cx, x1h, x1l, 1024);
  gbar(cnt, gen, nblk);

  // ---- P2: x2 partials = x1 @ W2^T, N=512, K=1024, S=16 (grid 4n*4m*16z)
  gemm_phase(smem, x1h, x1l, W2h, W2l, Psm, 512, 1024, 16, 4);
  gbar(cnt, gen, nblk);

  // ---- P3: kwta x2 (+b2) -> x2h/l
  kwta_phase(smem, Psm, 512, 0, 16, b2, cx, x2h, x2l, 512);
  gbar(cnt, gen, nblk);

  // ---- P4: x3 partials = x2 @ W3^T, N=1024, K=512, S=8 (8n*4m*8z)
  gemm_phase(smem, x2h, x2l, W3h, W3l, Psm, 1024, 512, 8, 8);
  gbar(cnt, gen, nblk);

  // ---- P5: kwta x3 (+b3) -> x3h/l
  kwta_phase(smem, Psm, 1024, 0, 8, b3, cx, x3h, x3l, 1024);
  gbar(cnt, gen, nblk);

  // ---- P6: out partials = x3 @ W4^T, N=1024, K=1024, S=8 (8n*4m*8z)
  gemm_phase(smem, x3h, x3l, W4h, W4l, Psm, 1024, 1024, 8, 8);
  gbar(cnt, gen, nblk);

  // ---- P7: reduce out (2 elems/thread)
  {
    const int base = blk * 512 + t;
#pragma unroll
    for (int u = 0; u < 2; ++u) {
      const int idx = base + u * 131072;
      float s = 0.f;
#pragma unroll
      for (int z = 0; z < 8; ++z) s += Psm[(size_t)z * 262144 + idx];
      out[idx] = s;
    }
  }
}

extern "C" void kernel_launch(void* const* d_in, const int* in_sizes, int n_in,
                              void* d_out, int out_size, void* d_ws, size_t ws_size,
                              hipStream_t stream) {
  const float* input = (const float*)d_in[0];
  const float* W_c1  = (const float*)d_in[1];
  const float* b_c1  = (const float*)d_in[2];
  const float* W_c2  = (const float*)d_in[3];
  const float* W1    = (const float*)d_in[4];
  const float* b1    = (const float*)d_in[5];
  const float* W2    = (const float*)d_in[6];
  const float* b2    = (const float*)d_in[7];
  const float* W3    = (const float*)d_in[8];
  const float* b3    = (const float*)d_in[9];
  const float* W4    = (const float*)d_in[10];
  float* out = (float*)d_out;

  char* wsb = (char*)d_ws;
  size_t off = 0;
  auto alloc = [&](size_t bytes) {
    char* p = wsb + off;
    off += (bytes + 255) & ~(size_t)255;
    return p;
  };
  int*   syncp = (int*)alloc(256);
  float* cx  = (float*)alloc(1024);
  short* x1h = (short*)alloc(524288);  short* x1l = (short*)alloc(524288);
  short* x2h = (short*)alloc(262144);  short* x2l = (short*)alloc(262144);
  short* x3h = (short*)alloc(524288);  short* x3l = (short*)alloc(524288);
  short* W2h = (short*)alloc(1048576); short* W2l = (short*)alloc(1048576);
  short* W3h = (short*)alloc(1048576); short* W3l = (short*)alloc(1048576);
  short* W4h = (short*)alloc(2097152); short* W4l = (short*)alloc(2097152);
  int S_big = 32;
  while (S_big > 8 && off + (size_t)S_big * 1572864ull > ws_size) S_big >>= 1;
  float* P = (float*)(wsb + off);  // big partials; later reused for small partials

  hipMemsetAsync(syncp, 0, 256, stream);

  {
    dim3 g(12, S_big);
    big_gemm3<<<g, 512, 0, stream>>>(input, W_c1, W1, P, 1024 / S_big);
  }

  mega_tail<<<256, 512, 0, stream>>>(
      P, S_big, W2, W3, W4, b_c1, W_c2, b1, b2, b3,
      syncp, cx, x1h, x1l, x2h, x2l, x3h, x3l,
      W2h, W2l, W3h, W3l, W4h, W4l, P, out);
}

// Round 5
// 567.681 us; speedup vs baseline: 1.2109x; 1.2109x over previous
//
#include <hip/hip_runtime.h>
#include <math.h>

// B=256, S2=32768, HID=512, HEADS=1024
// c1 = tanh(in@W_c1^T+b_c1); cx = sigmoid(c1@W_c2^T); x1 = kwta(in@W1^T+b1, cx*1024)
// x2 = kwta(x1@W2^T+b2, cx*512); x3 = kwta(x2@W3^T+b3, cx*1024); out = x3@W4^T
//
// All GEMMs: split-bf16 3-term MFMA (hi*hi + hi*lo + lo*hi), fp32 accumulate.
// Big GEMM: BM=256 (weights read ONCE), XCD-swizzled z-chunks (A k-chunk L2-local),
// split-K partials. Tail: fragment-major bf16 hi/lo arrays -> small GEMMs are
// LDS-free, barrier-free, no split-K, no partial-reduce kernels.
//
// Fragment layout (16x16x32, R2-verified): element (row, k) lives at
//   addr = ((tile(row>>4) * KB + (k>>5)) * 64 + (row&15) + ((k>>3)&3)*16) * 8 + (k&7)
// so a wave's lane l reads 16 B at ((tile*KB+kb)*64 + l)*8  (perfectly coalesced).

typedef __attribute__((ext_vector_type(8))) short bf16x8;
typedef __attribute__((ext_vector_type(4))) float f32x4;
typedef __attribute__((ext_vector_type(16))) float f32x16;

__device__ __forceinline__ void split2(float f0, float f1, unsigned& hi, unsigned& lo) {
  unsigned u0 = __float_as_uint(f0), u1 = __float_as_uint(f1);
  hi = __builtin_amdgcn_perm(u1, u0, 0x07060302u);
  float r0 = f0 - __uint_as_float(u0 & 0xffff0000u);
  float r1 = f1 - __uint_as_float(u1 & 0xffff0000u);
  lo = __builtin_amdgcn_perm(__float_as_uint(r1), __float_as_uint(r0), 0x07060302u);
}

__device__ __forceinline__ void split8(const float* v, bf16x8& h, bf16x8& l) {
#pragma unroll
  for (int e = 0; e < 8; ++e) {
    const unsigned u = __float_as_uint(v[e]);
    h[e] = (short)(unsigned short)(u >> 16);
    const float r = v[e] - __uint_as_float(u & 0xffff0000u);
    l[e] = (short)(unsigned short)(__float_as_uint(r) >> 16);
  }
}

// ---------------------------------------------------------------------------
// presplit_w: W2 (512x1024), W3 (1024x512), W4 (1024x1024) -> frag-major bf16
// hi/lo. One k-octet (8 elements) per thread; 262144 octets -> 1024 blocks.
// ---------------------------------------------------------------------------
__global__ __launch_bounds__(256) void presplit_w(
    const float* __restrict__ W2, const float* __restrict__ W3,
    const float* __restrict__ W4, short* __restrict__ W2h, short* __restrict__ W2l,
    short* __restrict__ W3h, short* __restrict__ W3l,
    short* __restrict__ W4h, short* __restrict__ W4l) {
  const int o = blockIdx.x * 256 + threadIdx.x;
  const float* src; short *dh, *dl; int K, kOctShift, rel;
  if (o < 65536) { src = W2; dh = W2h; dl = W2l; K = 1024; kOctShift = 7; rel = o; }
  else if (o < 131072) { src = W3; dh = W3h; dl = W3l; K = 512; kOctShift = 6; rel = o - 65536; }
  else { src = W4; dh = W4h; dl = W4l; K = 1024; kOctShift = 7; rel = o - 131072; }
  const int n = rel >> kOctShift;
  const int k = (rel & ((1 << kOctShift) - 1)) * 8;
  float v[8];
  *(float4*)v = *(const float4*)(src + (size_t)n * K + k);
  *(float4*)(v + 4) = *(const float4*)(src + (size_t)n * K + k + 4);
  bf16x8 h, l;
  split8(v, h, l);
  const int KB = K >> 5;
  const size_t addr = (((size_t)(n >> 4) * KB + (k >> 5)) * 64 + (n & 15) + ((k >> 3) & 3) * 16) * 8;
  *(bf16x8*)(dh + addr) = h;
  *(bf16x8*)(dl + addr) = l;
}

// ---------------------------------------------------------------------------
// big_gemm5: P[z] = A[256,32768] @ concat(W_c1,W1)[1536,32768]^T (K-chunk z)
// BM=256 (weights fetched once), BN=128, BK=32, 512 thr, 2 blocks/CU.
// XCD swizzle: blocks of one z-chunk pinned to one XCD -> A chunk L2-local.
// ---------------------------------------------------------------------------
__global__ __launch_bounds__(512, 4) void big_gemm5(
    const float* __restrict__ A, const float* __restrict__ Wc1,
    const float* __restrict__ W1, float* __restrict__ P, int S, int stepsPerZ) {
  __shared__ short sAh[256 * 40], sAl[256 * 40], sWh[128 * 40], sWl[128 * 40];
  const int tid = threadIdx.x;
  // swizzle: id = x(XCD) + 8*j ; z = x*(S/8) + j/12 ; n-block = j%12
  const int id = blockIdx.x;
  const int x = id & 7, j = id >> 3;
  const int z = x * (S >> 3) + j / 12;
  const int n0 = (j % 12) * 128;
  const float* Wp = (n0 < 512) ? (Wc1 + (size_t)n0 * 32768)
                               : (W1 + (size_t)(n0 - 512) * 32768);
  const int lane = tid & 63, wv = tid >> 6;
  const int wm = wv & 3, wn = wv >> 2;
  const int l31 = lane & 31, khalf = lane >> 5;

  const int arow = tid >> 1, acol = (tid & 1) * 16;  // A: 16 floats/thread
  const int wrow = tid >> 2, wcol = (tid & 3) * 8;   // W: 8 floats/thread
  const float* Ap = A + (size_t)arow * 32768 + acol;
  const float* Wq = Wp + (size_t)wrow * 32768 + wcol;

  f32x16 acc[2][2];
#pragma unroll
  for (int i = 0; i < 2; ++i)
#pragma unroll
    for (int jj = 0; jj < 2; ++jj)
#pragma unroll
      for (int r = 0; r < 16; ++r) acc[i][jj][r] = 0.f;

  int kk = z * stepsPerZ * 32;
  for (int s = 0; s < stepsPerZ; ++s, kk += 32) {
#pragma unroll
    for (int c = 0; c < 4; ++c) {
      const float4 v = *(const float4*)(Ap + kk + c * 4);
      unsigned h0, l0, h1, l1;
      split2(v.x, v.y, h0, l0);
      split2(v.z, v.w, h1, l1);
      *(uint2*)(&sAh[arow * 40 + acol + c * 4]) = (uint2){h0, h1};
      *(uint2*)(&sAl[arow * 40 + acol + c * 4]) = (uint2){l0, l1};
    }
#pragma unroll
    for (int c = 0; c < 2; ++c) {
      const float4 v = *(const float4*)(Wq + kk + c * 4);
      unsigned h0, l0, h1, l1;
      split2(v.x, v.y, h0, l0);
      split2(v.z, v.w, h1, l1);
      *(uint2*)(&sWh[wrow * 40 + wcol + c * 4]) = (uint2){h0, h1};
      *(uint2*)(&sWl[wrow * 40 + wcol + c * 4]) = (uint2){l0, l1};
    }
    __syncthreads();
#pragma unroll
    for (int ks = 0; ks < 2; ++ks) {
      bf16x8 ah[2], al[2], wh[2], wl[2];
#pragma unroll
      for (int i = 0; i < 2; ++i) {
        const int off = (wm * 64 + i * 32 + l31) * 40 + ks * 16 + khalf * 8;
        ah[i] = *(const bf16x8*)&sAh[off];
        al[i] = *(const bf16x8*)&sAl[off];
      }
#pragma unroll
      for (int jj = 0; jj < 2; ++jj) {
        const int off = (wn * 64 + jj * 32 + l31) * 40 + ks * 16 + khalf * 8;
        wh[jj] = *(const bf16x8*)&sWh[off];
        wl[jj] = *(const bf16x8*)&sWl[off];
      }
#pragma unroll
      for (int i = 0; i < 2; ++i)
#pragma unroll
        for (int jj = 0; jj < 2; ++jj) {
          acc[i][jj] = __builtin_amdgcn_mfma_f32_32x32x16_bf16(ah[i], wh[jj], acc[i][jj], 0, 0, 0);
          acc[i][jj] = __builtin_amdgcn_mfma_f32_32x32x16_bf16(ah[i], wl[jj], acc[i][jj], 0, 0, 0);
          acc[i][jj] = __builtin_amdgcn_mfma_f32_32x32x16_bf16(al[i], wh[jj], acc[i][jj], 0, 0, 0);
        }
    }
    __syncthreads();
  }
  // C/D 32x32: col = lane&31, row = (r&3) + 8*(r>>2) + 4*(lane>>5)
#pragma unroll
  for (int i = 0; i < 2; ++i)
#pragma unroll
    for (int jj = 0; jj < 2; ++jj)
#pragma unroll
      for (int r = 0; r < 16; ++r) {
        const int m = wm * 64 + i * 32 + (r & 3) + 8 * (r >> 2) + 4 * khalf;
        const int n = n0 + wn * 64 + jj * 32 + l31;
        P[((size_t)z * 256 + m) * 1536 + n] = acc[i][jj][r];
      }
}

// ---------------------------------------------------------------------------
// kwta1_cx: per row r -- float4 split-K reduce of Pbig (all 1536 cols, +bias),
// cx = sigmoid(sum tanh(c1)*Wc2), kwta on cols 512..1535 (exact stable-argsort
// ties), emit x1 frag-major bf16 hi/lo. One Pbig pass. 1024 threads.
// ---------------------------------------------------------------------------
__global__ __launch_bounds__(1024) void kwta1_cx(
    const float* __restrict__ Pbig, int S, const float* __restrict__ b_c1,
    const float* __restrict__ b1, const float* __restrict__ Wc2,
    float* __restrict__ cxg, short* __restrict__ x1h, short* __restrict__ x1l) {
  __shared__ float sd[1536];
  __shared__ float red[16];
  __shared__ float cx_sh;
  const int r = blockIdx.x, t = threadIdx.x;
  if (t < 384) {
    const int c = t * 4;
    float s0 = 0.f, s1 = 0.f, s2 = 0.f, s3 = 0.f;
    for (int z = 0; z < S; ++z) {
      const float4 p = *(const float4*)(Pbig + ((size_t)z * 256 + r) * 1536 + c);
      s0 += p.x; s1 += p.y; s2 += p.z; s3 += p.w;
    }
    const float4 bb = (c < 512) ? *(const float4*)(b_c1 + c)
                                : *(const float4*)(b1 + c - 512);
    sd[c] = s0 + bb.x; sd[c + 1] = s1 + bb.y;
    sd[c + 2] = s2 + bb.z; sd[c + 3] = s3 + bb.w;
  }
  __syncthreads();
  float pc = 0.f;
  if (t < 512) pc = tanhf(sd[t]) * Wc2[t];
#pragma unroll
  for (int o = 32; o; o >>= 1) pc += __shfl_down(pc, o, 64);
  if ((t & 63) == 0) red[t >> 6] = pc;
  __syncthreads();
  if (t == 0) {
    float a = 0.f;
#pragma unroll
    for (int w = 0; w < 8; ++w) a += red[w];
    cx_sh = 1.f / (1.f + expf(-a));
    cxg[r] = cx_sh;
  }
  __syncthreads();
  const int k = (int)(cx_sh * 1024.f);
  const float v = sd[512 + t];
  int cnt = 0;
  const float4* s4 = (const float4*)(sd + 512);
  for (int i4 = 0; i4 < 256; ++i4) {
    const float4 e = s4[i4];
    const int b = i4 << 2;
    cnt += (e.x > v || (e.x == v && b < t));
    cnt += (e.y > v || (e.y == v && b + 1 < t));
    cnt += (e.z > v || (e.z == v && b + 2 < t));
    cnt += (e.w > v || (e.w == v && b + 3 < t));
  }
  const float o = (cnt < k) ? v : 0.f;
  __syncthreads();
  sd[512 + t] = o;
  __syncthreads();
  if (t < 128) {  // emit 128 k-octets, frag-major (K=1024 -> KB=32)
    bf16x8 h, l;
    split8(sd + 512 + t * 8, h, l);
    const int kb = t >> 2, lane = (r & 15) + (t & 3) * 16;
    const size_t addr = (((size_t)(r >> 4) * 32 + kb) * 64 + lane) * 8;
    *(bf16x8*)(x1h + addr) = h;
    *(bf16x8*)(x1l + addr) = l;
  }
}

// ---------------------------------------------------------------------------
// kwta_small: y (fp32 row-major, bias already applied) -> kwta -> frag-major
// bf16 hi/lo. n threads per block (512 or 1024), one block per row.
// ---------------------------------------------------------------------------
__global__ void kwta_small(const float* __restrict__ y,
                           const float* __restrict__ cxg,
                           short* __restrict__ xh, short* __restrict__ xl, int n) {
  extern __shared__ float sd[];
  const int r = blockIdx.x, t = threadIdx.x;
  const float v = y[(size_t)r * n + t];
  sd[t] = v;
  __syncthreads();
  const int k = (int)(cxg[r] * (float)n);
  int cnt = 0;
  const float4* s4 = (const float4*)sd;
  for (int i4 = 0; i4 < (n >> 2); ++i4) {
    const float4 e = s4[i4];
    const int b = i4 << 2;
    cnt += (e.x > v || (e.x == v && b < t));
    cnt += (e.y > v || (e.y == v && b + 1 < t));
    cnt += (e.z > v || (e.z == v && b + 2 < t));
    cnt += (e.w > v || (e.w == v && b + 3 < t));
  }
  const float o = (cnt < k) ? v : 0.f;
  __syncthreads();
  sd[t] = o;
  __syncthreads();
  if (t < (n >> 3)) {
    bf16x8 h, l;
    split8(sd + t * 8, h, l);
    const int KB = n >> 5;
    const int kb = t >> 2, lane = (r & 15) + (t & 3) * 16;
    const size_t addr = (((size_t)(r >> 4) * KB + kb) * 64 + lane) * 8;
    *(bf16x8*)(xh + addr) = h;
    *(bf16x8*)(xl + addr) = l;
  }
}

// ---------------------------------------------------------------------------
// gemm_frag: Y[256,N] = X @ W^T (+bias), operands in frag-major bf16 hi/lo.
// No LDS, no barriers, no split-K. Block 256 thr = 4 waves; wave = 16 rows x
// 64 cols (4 n-tiles). Grid (N/64, 4).
// ---------------------------------------------------------------------------
__global__ __launch_bounds__(256) void gemm_frag(
    const short* __restrict__ Xh, const short* __restrict__ Xl,
    const short* __restrict__ Wh, const short* __restrict__ Wl,
    const float* __restrict__ bias, float* __restrict__ Y, int N, int KB) {
  const int t = threadIdx.x, lane = t & 63, wv = t >> 6;
  const int mtile = blockIdx.y * 4 + wv;
  const int ntile0 = blockIdx.x * 4;
  f32x4 acc[4];
#pragma unroll
  for (int j = 0; j < 4; ++j) acc[j] = (f32x4){0.f, 0.f, 0.f, 0.f};

  const short* xh = Xh + ((size_t)mtile * KB) * 512 + lane * 8;
  const short* xl = Xl + ((size_t)mtile * KB) * 512 + lane * 8;
  const short* wh0 = Wh + ((size_t)ntile0 * KB) * 512 + lane * 8;
  const short* wl0 = Wl + ((size_t)ntile0 * KB) * 512 + lane * 8;

  for (int kb = 0; kb < KB; ++kb) {
    const bf16x8 ah = *(const bf16x8*)(xh + (size_t)kb * 512);
    const bf16x8 al = *(const bf16x8*)(xl + (size_t)kb * 512);
#pragma unroll
    for (int j = 0; j < 4; ++j) {
      const size_t wo = ((size_t)j * KB + kb) * 512;
      const bf16x8 wh = *(const bf16x8*)(wh0 + wo);
      const bf16x8 wl = *(const bf16x8*)(wl0 + wo);
      acc[j] = __builtin_amdgcn_mfma_f32_16x16x32_bf16(ah, wh, acc[j], 0, 0, 0);
      acc[j] = __builtin_amdgcn_mfma_f32_16x16x32_bf16(ah, wl, acc[j], 0, 0, 0);
      acc[j] = __builtin_amdgcn_mfma_f32_16x16x32_bf16(al, wh, acc[j], 0, 0, 0);
    }
  }
  // C/D 16x16: col = lane&15, row = (lane>>4)*4 + r
  const int q = lane >> 4, l15 = lane & 15;
#pragma unroll
  for (int j = 0; j < 4; ++j)
#pragma unroll
    for (int rr = 0; rr < 4; ++rr) {
      const int m = mtile * 16 + q * 4 + rr;
      const int n = blockIdx.x * 64 + j * 16 + l15;
      float val = acc[j][rr];
      if (bias) val += bias[n];
      Y[(size_t)m * N + n] = val;
    }
}

extern "C" void kernel_launch(void* const* d_in, const int* in_sizes, int n_in,
                              void* d_out, int out_size, void* d_ws, size_t ws_size,
                              hipStream_t stream) {
  const float* input = (const float*)d_in[0];
  const float* W_c1  = (const float*)d_in[1];
  const float* b_c1  = (const float*)d_in[2];
  const float* W_c2  = (const float*)d_in[3];
  const float* W1    = (const float*)d_in[4];
  const float* b1    = (const float*)d_in[5];
  const float* W2    = (const float*)d_in[6];
  const float* b2    = (const float*)d_in[7];
  const float* W3    = (const float*)d_in[8];
  const float* b3    = (const float*)d_in[9];
  const float* W4    = (const float*)d_in[10];
  float* out = (float*)d_out;

  char* wsb = (char*)d_ws;
  size_t off = 0;
  auto alloc = [&](size_t bytes) {
    char* p = wsb + off;
    off += (bytes + 255) & ~(size_t)255;
    return p;
  };
  float* cx  = (float*)alloc(1024);
  short* x1h = (short*)alloc(524288);  short* x1l = (short*)alloc(524288);
  short* x2h = (short*)alloc(262144);  short* x2l = (short*)alloc(262144);
  short* x3h = (short*)alloc(524288);  short* x3l = (short*)alloc(524288);
  short* W2h = (short*)alloc(1048576); short* W2l = (short*)alloc(1048576);
  short* W3h = (short*)alloc(1048576); short* W3l = (short*)alloc(1048576);
  short* W4h = (short*)alloc(2097152); short* W4l = (short*)alloc(2097152);
  int S_big = 32;
  while (S_big > 8 && off + (size_t)S_big * 1572864ull > ws_size) S_big >>= 1;
  float* P = (float*)(wsb + off);   // big-GEMM partials; dead after kwta1_cx
  float* y2 = P;                    // [256,512] fp32, aliases P
  float* y3 = P + 131072;           // [256,1024] fp32

  // 1. pre-split small weights into frag-major bf16 hi/lo
  presplit_w<<<1024, 256, 0, stream>>>(W2, W3, W4, W2h, W2l, W3h, W3l, W4h, W4l);

  // 2. big fused GEMM (c1-pre | x1-pre) -> P, XCD-swizzled split-K
  big_gemm5<<<12 * S_big, 512, 0, stream>>>(input, W_c1, W1, P, S_big, 1024 / S_big);

  // 3. fused reduce + cx + kwta(x1) + frag emit
  kwta1_cx<<<256, 1024, 0, stream>>>(P, S_big, b_c1, b1, W_c2, cx, x1h, x1l);

  // 4. y2 = x1 @ W2^T + b2   (N=512, K=1024)
  {
    dim3 g(8, 4);
    gemm_frag<<<g, 256, 0, stream>>>(x1h, x1l, W2h, W2l, b2, y2, 512, 32);
  }
  // 5. kwta(x2) -> frags
  kwta_small<<<256, 512, 512 * 4, stream>>>(y2, cx, x2h, x2l, 512);

  // 6. y3 = x2 @ W3^T + b3   (N=1024, K=512)
  {
    dim3 g(16, 4);
    gemm_frag<<<g, 256, 0, stream>>>(x2h, x2l, W3h, W3l, b3, y3, 1024, 16);
  }
  // 7. kwta(x3) -> frags
  kwta_small<<<256, 1024, 1024 * 4, stream>>>(y3, cx, x3h, x3l, 1024);

  // 8. out = x3 @ W4^T   (N=1024, K=1024)
  {
    dim3 g(16, 4);
    gemm_frag<<<g, 256, 0, stream>>>(x3h, x3l, W4h, W4l, nullptr, out, 1024, 32);
  }
}